// Round 17
// baseline (106.460 us; speedup 1.0000x reference)
//
#include <hip/hip_runtime.h>
#include <stdint.h>

// Problem constants
#define B_      16
#define N_      2048
#define M_      8192
#define ROWS    (B_ * N_)        // 32768
#define D_      8

// ---- MFMA min-score kernel tiling ----
#define QUARTERS 8               // A-grid splits (1024 anchors each)
#define APQ     (M_ / QUARTERS)  // 1024
#define CHUNK   256              // anchors per LDS chunk == rescan granularity
#define NCHUNK  (APQ / CHUNK)    // 4
#define NSPLIT  (M_ / CHUNK)     // 32 chunk-minima planes in wsv
#define TPC     (CHUNK / 16)     // 16 MFMA tiles per chunk
#define RT      8                // 16-row subtiles per wave (r17: 4->8)
#define WROWS   (RT * 16)        // 128 rows per wave
#define BROWS_A (4 * WROWS)      // 512 rows per block (4 waves)
#define GRIDX   (ROWS / BROWS_A) // 64 -> grid 64x8 = 512 blocks (2/CU)

// Packed-anchor plane layout (ws prep region and LDS buffer) -- UNCHANGED
#define OFF_NH  0                // [256][8] bf16 hi   (4 KB)
#define OFF_NM  4096             // [256][8] bf16 mid  (4 KB)
#define OFF_NL  8192             // [256][8] bf16 lo   (4 KB)
#define OFF_HN  12288            // [256]    f32 0.5*||a||^2 (1 KB)
#define CHUNK_BYTES 13312        // 13 KB = 13 segments of 1024 B
#define SMEM_BYTES 36864         // 36 KB declared (26 KB used)

// Rescan tiling
#define TPR     8                // threads per row
#define BROWS   32               // rows per rescan block

// History (hard-won; keep):
//  r0-r4: scalar VALU full-problem path pinned 59-76us. r5-r12: MFMA scores
//    verified; (min,idx) tracking paid ~100 AGPR-shuttle VALU/tile; FIVE
//    allocator levers refuted. r9: raw asm MFMA corrupts (hazard recognizer
//    blind to INLINEASM) -- never hand-emit MFMA.
//  r13: value-only tracking; exposed harness ws poison: 256MB fill =
//    ~40.4us/iter in the timed path, FIXED regardless of our ws usage.
//  r14: chunk-level minima + 256-anchor global rescan: 116 -> 109.2.
//  r16 (= r15 resubmitted after infra fail): OPERAND FLIP (anchors=A, x=B):
//    lane's 4 acc = 4 anchors of ONE row -> fmin-tree immediately; loop-
//    carried VALU state 16 -> 4 regs. A fell out of top-5 (<39.8us);
//    total 105.1. LESSON: shrink VALU-visible state; MFMA-INPUT state is
//    AGPR-safe (MFMA reads AGPRs natively).
//  r17 (this): rt 4 -> 8 (128 rows/wave). The 3 ds_read_b128 per tt now
//    feed 16 MFMAs: LDS-pipe wall 15.4 -> 7.7us/CU. Doubled state is all
//    MFMA-input (B1/B2, AGPR-safe); VALU-visible stays best[8]+acc. Grid
//    512 = 2 blocks/CU (vs r6's latency trap: now 8 independent rt chains
//    + 2x issue work per slot cover the ~200cy chain). Per-row math order
//    unchanged -> wsv bit-identical to r16.
//  MFMA numerics: x,-a split hi/mid/lo bf16 (RNE); two 16x16x32 MFMAs give
//  8 of 9 cross terms (hh,mh,hm,mm | lh,hl,lm,ml; drop ll); C-in = 0.5||a||^2.

typedef short bf16x8 __attribute__((ext_vector_type(8)));
typedef float f32x4  __attribute__((ext_vector_type(4)));

__device__ __forceinline__ unsigned short f2bf(float f) {   // RNE f32->bf16
    unsigned u = __float_as_uint(f);
    u += 0x7FFFu + ((u >> 16) & 1u);
    return (unsigned short)(u >> 16);
}
__device__ __forceinline__ float bf2f(unsigned short h) {
    return __uint_as_float(((unsigned)h) << 16);
}

// Prep: one thread per anchor; split negated anchor into bf16 hi/mid/lo +
// f32 half-norm. BIT-IDENTICAL to r5-r16 (verified passing).
__global__ __launch_bounds__(256) void prep_kernel(
    const float* __restrict__ anchors, char* __restrict__ pk)
{
    const int a = blockIdx.x * 256 + threadIdx.x;
    const float4* pa = (const float4*)(anchors + (size_t)a * D_);
    const float4 g0 = pa[0], g1 = pa[1];
    float nv[8] = {-g0.x, -g0.y, -g0.z, -g0.w, -g1.x, -g1.y, -g1.z, -g1.w};
    bf16x8 vh, vm, vl;
    #pragma unroll
    for (int k = 0; k < 8; ++k) {
        unsigned short h = f2bf(nv[k]);
        float r1 = nv[k] - bf2f(h);
        unsigned short m = f2bf(r1);
        float r2 = r1 - bf2f(m);
        unsigned short l = f2bf(r2);
        vh[k] = (short)h; vm[k] = (short)m; vl[k] = (short)l;
    }
    char* base = pk + (size_t)(a >> 8) * CHUNK_BYTES;
    const int i = a & 255;
    *(bf16x8*)(base + OFF_NH + i * 16) = vh;
    *(bf16x8*)(base + OFF_NM + i * 16) = vm;
    *(bf16x8*)(base + OFF_NL + i * 16) = vl;
    float nr = nv[0] * nv[0];
    #pragma unroll
    for (int k = 1; k < 8; ++k) nr = fmaf(nv[k], nv[k], nr);
    *(float*)(base + OFF_HN + i * 4) = 0.5f * nr;
}

// Kernel A: per-(row, 256-anchor chunk) MIN SCORE via split-bf16 MFMA,
// flipped operands (A = anchors from LDS, B = x in registers), RT=8.
// C/D layout (m89/m91): col = lane&15 (x-row), row = (lane>>4)*4+reg (anchor).
__global__ __launch_bounds__(256)
__attribute__((amdgpu_waves_per_eu(2, 2)))
void argmin_mfma_kernel(
    const float* __restrict__ x,        // [ROWS][8]
    const char*  __restrict__ pk,       // packed anchors, 32 chunks
    float* __restrict__ wsv)            // [NSPLIT][ROWS]
{
    __shared__ __align__(16) char smem[SMEM_BYTES];

    const int tid  = threadIdx.x;
    const int wave = tid >> 6;
    const int lane = tid & 63;
    const int n    = lane & 15;          // x-row col slot (C col)
    const int kb   = lane >> 4;          // k-block 0..3 (and C-row group)

    const int quarter = blockIdx.y;
    const int wrow0   = blockIdx.x * BROWS_A + wave * WROWS;

    const char* srcq = pk + (size_t)quarter * NCHUNK * CHUNK_BYTES;

    // Chunk-0 DMA first (latency hides under the x-fragment prologue).
    {
        char* bufw = smem;
        #pragma unroll
        for (int sg = 0; sg < 3; ++sg) {
            const int seg = (wave + sg * 4) * 1024;
            __builtin_amdgcn_global_load_lds(srcq + seg + lane * 16,
                                             bufw + seg, 16, 0, 0);
        }
        if (wave == 0)
            __builtin_amdgcn_global_load_lds(srcq + 12288 + lane * 16,
                                             bufw + 12288, 16, 0, 0);
    }

    // x fragments as B-operand, virtual K=32 slot packing:
    // B1 = [xh, xh, xm, xm] across kb; B2 = [xl, xh, xl, xm].
    // 64 VGPRs of MFMA-input state: AGPR-safe (MFMA reads AGPR natively).
    bf16x8 B1[RT], B2[RT];
    #pragma unroll
    for (int rt = 0; rt < RT; ++rt) {
        const int row = wrow0 + rt * 16 + n;
        const float4* px = (const float4*)(x + (size_t)row * D_);
        const float4 lo = px[0], hi = px[1];
        const float v[8] = {lo.x, lo.y, lo.z, lo.w, hi.x, hi.y, hi.z, hi.w};
        #pragma unroll
        for (int k = 0; k < 8; ++k) {
            unsigned short xh = f2bf(v[k]);
            float r1 = v[k] - bf2f(xh);
            unsigned short xm = f2bf(r1);
            float r2 = r1 - bf2f(xm);
            unsigned short xl = f2bf(r2);
            B1[rt][k] = (short)((kb < 2) ? xh : xm);
            B2[rt][k] = (short)((kb == 1) ? xh : ((kb == 3) ? xm : xl));
        }
    }

    // Anchor A-operand LDS offsets (plane selection per kb).
    const int o1 = (((kb & 1) == 1) ? OFF_NM : OFF_NH) + n * 16;
    const int o2 = (((kb & 1) == 1) ? OFF_NL : ((kb == 2) ? OFF_NM : OFF_NH)) + n * 16;
    const int oh = OFF_HN + kb * 16;     // 4 hn floats for this lane's anchors

    float best[RT];
    #pragma unroll
    for (int rt = 0; rt < RT; ++rt) best[rt] = 3.4e38f;

    __syncthreads();                     // drains chunk-0 DMA

    #pragma unroll 1
    for (int c = 0; c < NCHUNK; ++c) {
        const char* bufr = smem + (c & 1) * CHUNK_BYTES;

        if (c < NCHUNK - 1) {            // prefetch next chunk via DMA
            char* bufw = smem + ((c & 1) ^ 1) * CHUNK_BYTES;
            const char* g = srcq + (size_t)(c + 1) * CHUNK_BYTES;
            #pragma unroll
            for (int sg = 0; sg < 3; ++sg) {
                const int seg = (wave + sg * 4) * 1024;
                __builtin_amdgcn_global_load_lds(g + seg + lane * 16,
                                                 bufw + seg, 16, 0, 0);
            }
            if (wave == 0)
                __builtin_amdgcn_global_load_lds(g + 12288 + lane * 16,
                                                 bufw + 12288, 16, 0, 0);
        }

        #pragma unroll 2
        for (int tt = 0; tt < TPC; ++tt) {
            const bf16x8 a1  = *(const bf16x8*)(bufr + o1 + tt * 256);
            const bf16x8 a2  = *(const bf16x8*)(bufr + o2 + tt * 256);
            const f32x4  hnv = *(const f32x4*)(bufr + oh + tt * 64);
            #pragma unroll
            for (int rt = 0; rt < RT; ++rt) {
                f32x4 acc = __builtin_amdgcn_mfma_f32_16x16x32_bf16(a1, B1[rt], hnv, 0, 0, 0);
                acc = __builtin_amdgcn_mfma_f32_16x16x32_bf16(a2, B2[rt], acc, 0, 0, 0);
                // 4 acc = 4 anchors of ONE x-row -> reduce immediately.
                const float m01 = fminf(acc[0], acc[1]);
                const float m23 = fminf(acc[2], acc[3]);
                best[rt] = fminf(best[rt], fminf(m01, m23));
            }
        }

        // Per-chunk epilogue: min across the 4 kb-groups (lanes n, n+16,
        // n+32, n+48), write plane s = quarter*4 + c, reset.
        #pragma unroll
        for (int rt = 0; rt < RT; ++rt) {
            float bv = best[rt];
            bv = fminf(bv, __shfl_xor(bv, 16));
            bv = fminf(bv, __shfl_xor(bv, 32));
            if (lane < 16) {
                wsv[(size_t)(quarter * NCHUNK + c) * ROWS
                    + (wrow0 + rt * 16 + lane)] = bv;
            }
            best[rt] = 3.4e38f;
        }

        __syncthreads();
    }
}

// Rescan: per row, pick the winning 256-anchor chunk (strict '<' over the 32
// chunk-minima in ascending order -> lowest chunk on ties), then exact-f32
// rescan of that chunk from GLOBAL (L2-resident) with first-occurrence
// (min, idx) tracking; fused q_sample blend. UNCHANGED from r14/r16 (passing).
__global__ __launch_bounds__(256) void rescan_kernel(
    const float* __restrict__ x,
    const float* __restrict__ anchors,
    const float* __restrict__ sa_tab,
    const float* __restrict__ sb_tab,
    const int*   __restrict__ t,
    const float* __restrict__ wsv,      // [NSPLIT][ROWS]
    float* __restrict__ out)
{
    const int tid  = threadIdx.x;
    const int g    = tid & (TPR - 1);
    const int rloc = tid >> 3;
    const int row  = blockIdx.x * BROWS + rloc;

    // Phase 1: winner chunk (ascending scan -> lowest chunk on ties)
    float bs = 3.4e38f;
    int   bsp = 0;
    #pragma unroll
    for (int k = 0; k < NSPLIT / TPR; ++k) {
        const int s = g + k * TPR;
        const float v = wsv[(size_t)s * ROWS + row];
        const bool c = v < bs;
        bs  = c ? v : bs;
        bsp = c ? s : bsp;
    }
    #pragma unroll
    for (int m = 1; m < TPR; m <<= 1) {
        const float ov  = __shfl_xor(bs, m);
        const int   osp = __shfl_xor(bsp, m);
        const bool take = (ov < bs) || (ov == bs && osp < bsp);
        bs  = take ? ov  : bs;
        bsp = take ? osp : bsp;
    }
    const int base = bsp * CHUNK;

    // My row
    const float4* px = (const float4*)(x + (size_t)row * D_);
    const float4 xlo = px[0], xhi = px[1];
    const float X0 = xlo.x, X1 = xlo.y, X2 = xlo.z, X3 = xlo.w;
    const float X4 = xhi.x, X5 = xhi.y, X6 = xhi.z, X7 = xhi.w;

    // Phase 2: exact f32 rescan of 256 anchors (r0-r4's exact chain)
    float bv = 3.4e38f;
    int   bi = 0x7FFFFFFF;
    #pragma unroll 4
    for (int j = 0; j < CHUNK / TPR; ++j) {
        const int ai = base + j * TPR + g;
        const float4* pa = (const float4*)(anchors + (size_t)ai * D_);
        const float4 g0 = pa[0], g1 = pa[1];
        const float na0 = -g0.x, na1 = -g0.y, na2 = -g0.z, na3 = -g0.w;
        const float na4 = -g1.x, na5 = -g1.y, na6 = -g1.z, na7 = -g1.w;
        float nr = na0 * na0;
        nr = fmaf(na1, na1, nr);
        nr = fmaf(na2, na2, nr);
        nr = fmaf(na3, na3, nr);
        nr = fmaf(na4, na4, nr);
        nr = fmaf(na5, na5, nr);
        nr = fmaf(na6, na6, nr);
        nr = fmaf(na7, na7, nr);
        const float hn = 0.5f * nr;
        float s = fmaf(X0, na0, hn);
        s = fmaf(X1, na1, s);
        s = fmaf(X2, na2, s);
        s = fmaf(X3, na3, s);
        s = fmaf(X4, na4, s);
        s = fmaf(X5, na5, s);
        s = fmaf(X6, na6, s);
        s = fmaf(X7, na7, s);
        const bool lt = s < bv;
        bv = lt ? s  : bv;
        bi = lt ? ai : bi;
    }
    #pragma unroll
    for (int m = 1; m < TPR; m <<= 1) {
        const float ov = __shfl_xor(bv, m);
        const int   oi = __shfl_xor(bi, m);
        const bool take = (ov < bv) || (ov == bv && oi < bi);
        bv = take ? ov : bv;
        bi = take ? oi : bi;
    }

    // Phase 3: one lane per row writes the fused output
    if (g == 0) {
        const int b  = row >> 11;               // row / N_
        const int tb = t[b];
        const float sa = sa_tab[tb];
        const float sb = sb_tab[tb];

        const float4* pa = (const float4*)(anchors + (size_t)bi * D_);
        const float4 a0 = pa[0], a1 = pa[1];

        float4 o0, o1;
        o0.x = fmaf(sa, xlo.x, sb * a0.x);
        o0.y = fmaf(sa, xlo.y, sb * a0.y);
        o0.z = fmaf(sa, xlo.z, sb * a0.z);
        o0.w = fmaf(sa, xlo.w, sb * a0.w);
        o1.x = fmaf(sa, xhi.x, sb * a1.x);
        o1.y = fmaf(sa, xhi.y, sb * a1.y);
        o1.z = fmaf(sa, xhi.z, sb * a1.z);
        o1.w = fmaf(sa, xhi.w, sb * a1.w);

        float4* po = (float4*)(out + (size_t)row * D_);
        po[0] = o0;
        po[1] = o1;
    }
}

extern "C" void kernel_launch(void* const* d_in, const int* in_sizes, int n_in,
                              void* d_out, int out_size, void* d_ws, size_t ws_size,
                              hipStream_t stream) {
    const float* x       = (const float*)d_in[0];  // x_start [16,2048,4,2]
    const float* anchors = (const float*)d_in[1];  // anchors [8192,4,2]
    const float* sa_tab  = (const float*)d_in[2];  // sqrt_alphas_cumprod [1000]
    const float* sb_tab  = (const float*)d_in[3];  // sqrt_one_minus_alphas_cumprod [1000]
    const int*   t       = (const int*)d_in[4];    // t [16]
    float* out = (float*)d_out;

    // ws layout: wsv [32][ROWS] f32 = 4MB @0, packed anchors 426KB @4MB
    float* wsv = (float*)d_ws;
    char*  pk  = (char*)d_ws + (size_t)4 * 1024 * 1024;

    prep_kernel<<<M_ / 256, 256, 0, stream>>>(anchors, pk);

    dim3 gridA(GRIDX, QUARTERS);   // 64 x 8 = 512 blocks (2/CU)
    argmin_mfma_kernel<<<gridA, 256, 0, stream>>>(x, pk, wsv);

    rescan_kernel<<<ROWS / BROWS, 256, 0, stream>>>(
        x, anchors, sa_tab, sb_tab, t, wsv, out);
}

// Round 18
// 104.412 us; speedup vs baseline: 1.0196x; 1.0196x over previous
//
#include <hip/hip_runtime.h>
#include <stdint.h>

// Problem constants
#define B_      16
#define N_      2048
#define M_      8192
#define ROWS    (B_ * N_)        // 32768
#define D_      8

// ---- MFMA min-score kernel tiling ----
#define QUARTERS 8               // A-grid splits (1024 anchors each)
#define APQ     (M_ / QUARTERS)  // 1024
#define CHUNK   256              // anchors per LDS chunk == rescan granularity
#define NCHUNK  (APQ / CHUNK)    // 4
#define NSPLIT  (M_ / CHUNK)     // 32 chunk-minima planes in wsv
#define TPC     (CHUNK / 16)     // 16 MFMA tiles per chunk
#define BROWS_A 256              // rows per block (4 waves x 64 rows)
#define GRIDX   (ROWS / BROWS_A) // 128 -> grid 128x8 = 1024 blocks (4/CU)

// Packed-anchor plane layout (ws prep region and LDS buffer)
#define OFF_NH  0                // [256][8] bf16 hi   (4 KB)
#define OFF_NM  4096             // [256][8] bf16 mid  (4 KB)
#define OFF_NL  8192             // [256][8] bf16 lo   (4 KB)
#define OFF_HN  12288            // [256]    f32 0.5*||a||^2 (1 KB)
#define CHUNK_BYTES 13312        // 13 KB = 13 segments of 1024 B
#define SMEM_BYTES 36864         // 36 KB declared (26 KB used)

// Rescan tiling
#define TPR     8                // threads per row
#define BROWS   32               // rows per rescan block

// History (hard-won; keep) -- FINAL STATE (r16 config, session best 105.1us):
//  r0-r4: scalar VALU full-problem path pinned 59-76us (practical v_fma
//    ceiling ~103 TF; r4 hit 64us @ 90% busy = ~75% of that roofline).
//  r5-r12: MFMA split-bf16 scores verified; (min,idx) tracking paid ~100
//    AGPR-shuttle VALU/tile; SIX allocator levers refuted (launch_bounds,
//    waves_per_eu, LDS governor, asm operand pinning, unroll, +r17 RT=8).
//    r9: raw asm MFMA corrupts (hazard recognizer blind to INLINEASM).
//  r13: value-only tracking; exposed harness ws poison: 256MB fill =
//    ~40.4us/iter in the timed path, FIXED regardless of our ws usage.
//  r14: chunk-level minima + 256-anchor global-read exact-f32 rescan:
//    116 -> 109.2.
//  r16: OPERAND FLIP (anchors=A, x=B): lane's 4 acc = 4 anchors of ONE row
//    -> fmin-tree immediately; loop-carried VALU state 16 -> 4 regs.
//    A fell out of top-5 (<39.8us); total 105.1. LESSON: shrink the
//    VALU-visible loop state; MFMA-INPUT state is AGPR-safe.
//  r17: RT 4->8 (halved LDS wall, 2 blocks/CU): NEUTRAL (106.5) -- latency
//    regime ate the traffic gain. Reverted.
//  Structural plateau: fill 40 + harness overhead ~13 + A ~35 + rescan ~10
//    + prep ~2 = ~105us. Remaining A headroom (~15us) requires r9-class
//    risk (producer-consumer waves / asm scheduling) for <10% of total.
//  MFMA numerics: x,-a split hi/mid/lo bf16 (RNE); two 16x16x32 MFMAs give
//  8 of 9 cross terms (hh,mh,hm,mm | lh,hl,lm,ml; drop ll); C-in = 0.5||a||^2.

typedef short bf16x8 __attribute__((ext_vector_type(8)));
typedef float f32x4  __attribute__((ext_vector_type(4)));

__device__ __forceinline__ unsigned short f2bf(float f) {   // RNE f32->bf16
    unsigned u = __float_as_uint(f);
    u += 0x7FFFu + ((u >> 16) & 1u);
    return (unsigned short)(u >> 16);
}
__device__ __forceinline__ float bf2f(unsigned short h) {
    return __uint_as_float(((unsigned)h) << 16);
}

// Prep: one thread per anchor; split negated anchor into bf16 hi/mid/lo +
// f32 half-norm. BIT-IDENTICAL to r5-r16 (verified passing).
__global__ __launch_bounds__(256) void prep_kernel(
    const float* __restrict__ anchors, char* __restrict__ pk)
{
    const int a = blockIdx.x * 256 + threadIdx.x;
    const float4* pa = (const float4*)(anchors + (size_t)a * D_);
    const float4 g0 = pa[0], g1 = pa[1];
    float nv[8] = {-g0.x, -g0.y, -g0.z, -g0.w, -g1.x, -g1.y, -g1.z, -g1.w};
    bf16x8 vh, vm, vl;
    #pragma unroll
    for (int k = 0; k < 8; ++k) {
        unsigned short h = f2bf(nv[k]);
        float r1 = nv[k] - bf2f(h);
        unsigned short m = f2bf(r1);
        float r2 = r1 - bf2f(m);
        unsigned short l = f2bf(r2);
        vh[k] = (short)h; vm[k] = (short)m; vl[k] = (short)l;
    }
    char* base = pk + (size_t)(a >> 8) * CHUNK_BYTES;
    const int i = a & 255;
    *(bf16x8*)(base + OFF_NH + i * 16) = vh;
    *(bf16x8*)(base + OFF_NM + i * 16) = vm;
    *(bf16x8*)(base + OFF_NL + i * 16) = vl;
    float nr = nv[0] * nv[0];
    #pragma unroll
    for (int k = 1; k < 8; ++k) nr = fmaf(nv[k], nv[k], nr);
    *(float*)(base + OFF_HN + i * 4) = 0.5f * nr;
}

// Kernel A: per-(row, 256-anchor chunk) MIN SCORE via split-bf16 MFMA with
// FLIPPED operands: A = anchors (LDS), B = x (registers).
// C/D layout (m89/m91): col = lane&15 (x-row), row = (lane>>4)*4+reg (anchor).
__global__ __launch_bounds__(256)
__attribute__((amdgpu_waves_per_eu(4, 4)))
void argmin_mfma_kernel(
    const float* __restrict__ x,        // [ROWS][8]
    const char*  __restrict__ pk,       // packed anchors, 32 chunks
    float* __restrict__ wsv)            // [NSPLIT][ROWS]
{
    __shared__ __align__(16) char smem[SMEM_BYTES];

    const int tid  = threadIdx.x;
    const int wave = tid >> 6;
    const int lane = tid & 63;
    const int n    = lane & 15;          // x-row col slot (C col)
    const int kb   = lane >> 4;          // k-block 0..3 (and C-row group)

    const int quarter = blockIdx.y;
    const int wrow0   = blockIdx.x * BROWS_A + wave * 64;

    const char* srcq = pk + (size_t)quarter * NCHUNK * CHUNK_BYTES;

    // Chunk-0 DMA first (latency hides under the x-fragment prologue).
    {
        char* bufw = smem;
        #pragma unroll
        for (int sg = 0; sg < 3; ++sg) {
            const int seg = (wave + sg * 4) * 1024;
            __builtin_amdgcn_global_load_lds(srcq + seg + lane * 16,
                                             bufw + seg, 16, 0, 0);
        }
        if (wave == 0)
            __builtin_amdgcn_global_load_lds(srcq + 12288 + lane * 16,
                                             bufw + 12288, 16, 0, 0);
    }

    // x fragments as B-operand, virtual K=32 slot packing:
    // B1 = [xh, xh, xm, xm] across kb; B2 = [xl, xh, xl, xm].
    // (Anchor side at read time: A1 = [nh, nm, nh, nm]; A2 = [nh, nl, nm, nl].
    //  Slot products: MFMA1 -> hh, mh, hm, mm; MFMA2 -> lh, hl, lm, ml.)
    bf16x8 B1[4], B2[4];
    #pragma unroll
    for (int rt = 0; rt < 4; ++rt) {
        const int row = wrow0 + rt * 16 + n;
        const float4* px = (const float4*)(x + (size_t)row * D_);
        const float4 lo = px[0], hi = px[1];
        const float v[8] = {lo.x, lo.y, lo.z, lo.w, hi.x, hi.y, hi.z, hi.w};
        #pragma unroll
        for (int k = 0; k < 8; ++k) {
            unsigned short xh = f2bf(v[k]);
            float r1 = v[k] - bf2f(xh);
            unsigned short xm = f2bf(r1);
            float r2 = r1 - bf2f(xm);
            unsigned short xl = f2bf(r2);
            B1[rt][k] = (short)((kb < 2) ? xh : xm);
            B2[rt][k] = (short)((kb == 1) ? xh : ((kb == 3) ? xm : xl));
        }
    }

    // Anchor A-operand LDS offsets (plane selection per kb).
    const int o1 = (((kb & 1) == 1) ? OFF_NM : OFF_NH) + n * 16;
    const int o2 = (((kb & 1) == 1) ? OFF_NL : ((kb == 2) ? OFF_NM : OFF_NH)) + n * 16;
    const int oh = OFF_HN + kb * 16;     // 4 hn floats for this lane's anchors

    float best[4];
    #pragma unroll
    for (int rt = 0; rt < 4; ++rt) best[rt] = 3.4e38f;

    __syncthreads();                     // drains chunk-0 DMA

    #pragma unroll 1
    for (int c = 0; c < NCHUNK; ++c) {
        const char* bufr = smem + (c & 1) * CHUNK_BYTES;

        if (c < NCHUNK - 1) {            // prefetch next chunk via DMA
            char* bufw = smem + ((c & 1) ^ 1) * CHUNK_BYTES;
            const char* g = srcq + (size_t)(c + 1) * CHUNK_BYTES;
            #pragma unroll
            for (int sg = 0; sg < 3; ++sg) {
                const int seg = (wave + sg * 4) * 1024;
                __builtin_amdgcn_global_load_lds(g + seg + lane * 16,
                                                 bufw + seg, 16, 0, 0);
            }
            if (wave == 0)
                __builtin_amdgcn_global_load_lds(g + 12288 + lane * 16,
                                                 bufw + 12288, 16, 0, 0);
        }

        #pragma unroll 2
        for (int tt = 0; tt < TPC; ++tt) {
            const bf16x8 a1  = *(const bf16x8*)(bufr + o1 + tt * 256);
            const bf16x8 a2  = *(const bf16x8*)(bufr + o2 + tt * 256);
            const f32x4  hnv = *(const f32x4*)(bufr + oh + tt * 64);
            #pragma unroll
            for (int rt = 0; rt < 4; ++rt) {
                f32x4 acc = __builtin_amdgcn_mfma_f32_16x16x32_bf16(a1, B1[rt], hnv, 0, 0, 0);
                acc = __builtin_amdgcn_mfma_f32_16x16x32_bf16(a2, B2[rt], acc, 0, 0, 0);
                // 4 acc = 4 anchors of ONE x-row -> reduce immediately.
                const float m01 = fminf(acc[0], acc[1]);
                const float m23 = fminf(acc[2], acc[3]);
                best[rt] = fminf(best[rt], fminf(m01, m23));
            }
        }

        // Per-chunk epilogue: min across the 4 kb-groups (lanes n, n+16,
        // n+32, n+48), write plane s = quarter*4 + c, reset.
        #pragma unroll
        for (int rt = 0; rt < 4; ++rt) {
            float bv = best[rt];
            bv = fminf(bv, __shfl_xor(bv, 16));
            bv = fminf(bv, __shfl_xor(bv, 32));
            if (lane < 16) {
                wsv[(size_t)(quarter * NCHUNK + c) * ROWS
                    + (wrow0 + rt * 16 + lane)] = bv;
            }
            best[rt] = 3.4e38f;
        }

        __syncthreads();
    }
}

// Rescan: per row, pick the winning 256-anchor chunk (strict '<' over the 32
// chunk-minima in ascending order -> lowest chunk on ties), then exact-f32
// rescan of that chunk from GLOBAL (L2-resident) with first-occurrence
// (min, idx) tracking; fused q_sample blend.
__global__ __launch_bounds__(256) void rescan_kernel(
    const float* __restrict__ x,
    const float* __restrict__ anchors,
    const float* __restrict__ sa_tab,
    const float* __restrict__ sb_tab,
    const int*   __restrict__ t,
    const float* __restrict__ wsv,      // [NSPLIT][ROWS]
    float* __restrict__ out)
{
    const int tid  = threadIdx.x;
    const int g    = tid & (TPR - 1);
    const int rloc = tid >> 3;
    const int row  = blockIdx.x * BROWS + rloc;

    // Phase 1: winner chunk (ascending scan -> lowest chunk on ties)
    float bs = 3.4e38f;
    int   bsp = 0;
    #pragma unroll
    for (int k = 0; k < NSPLIT / TPR; ++k) {
        const int s = g + k * TPR;
        const float v = wsv[(size_t)s * ROWS + row];
        const bool c = v < bs;
        bs  = c ? v : bs;
        bsp = c ? s : bsp;
    }
    #pragma unroll
    for (int m = 1; m < TPR; m <<= 1) {
        const float ov  = __shfl_xor(bs, m);
        const int   osp = __shfl_xor(bsp, m);
        const bool take = (ov < bs) || (ov == bs && osp < bsp);
        bs  = take ? ov  : bs;
        bsp = take ? osp : bsp;
    }
    const int base = bsp * CHUNK;

    // My row
    const float4* px = (const float4*)(x + (size_t)row * D_);
    const float4 xlo = px[0], xhi = px[1];
    const float X0 = xlo.x, X1 = xlo.y, X2 = xlo.z, X3 = xlo.w;
    const float X4 = xhi.x, X5 = xhi.y, X6 = xhi.z, X7 = xhi.w;

    // Phase 2: exact f32 rescan of 256 anchors (r0-r4's exact chain)
    float bv = 3.4e38f;
    int   bi = 0x7FFFFFFF;
    #pragma unroll 4
    for (int j = 0; j < CHUNK / TPR; ++j) {
        const int ai = base + j * TPR + g;
        const float4* pa = (const float4*)(anchors + (size_t)ai * D_);
        const float4 g0 = pa[0], g1 = pa[1];
        const float na0 = -g0.x, na1 = -g0.y, na2 = -g0.z, na3 = -g0.w;
        const float na4 = -g1.x, na5 = -g1.y, na6 = -g1.z, na7 = -g1.w;
        float nr = na0 * na0;
        nr = fmaf(na1, na1, nr);
        nr = fmaf(na2, na2, nr);
        nr = fmaf(na3, na3, nr);
        nr = fmaf(na4, na4, nr);
        nr = fmaf(na5, na5, nr);
        nr = fmaf(na6, na6, nr);
        nr = fmaf(na7, na7, nr);
        const float hn = 0.5f * nr;
        float s = fmaf(X0, na0, hn);
        s = fmaf(X1, na1, s);
        s = fmaf(X2, na2, s);
        s = fmaf(X3, na3, s);
        s = fmaf(X4, na4, s);
        s = fmaf(X5, na5, s);
        s = fmaf(X6, na6, s);
        s = fmaf(X7, na7, s);
        const bool lt = s < bv;
        bv = lt ? s  : bv;
        bi = lt ? ai : bi;
    }
    #pragma unroll
    for (int m = 1; m < TPR; m <<= 1) {
        const float ov = __shfl_xor(bv, m);
        const int   oi = __shfl_xor(bi, m);
        const bool take = (ov < bv) || (ov == bv && oi < bi);
        bv = take ? ov : bv;
        bi = take ? oi : bi;
    }

    // Phase 3: one lane per row writes the fused output
    if (g == 0) {
        const int b  = row >> 11;               // row / N_
        const int tb = t[b];
        const float sa = sa_tab[tb];
        const float sb = sb_tab[tb];

        const float4* pa = (const float4*)(anchors + (size_t)bi * D_);
        const float4 a0 = pa[0], a1 = pa[1];

        float4 o0, o1;
        o0.x = fmaf(sa, xlo.x, sb * a0.x);
        o0.y = fmaf(sa, xlo.y, sb * a0.y);
        o0.z = fmaf(sa, xlo.z, sb * a0.z);
        o0.w = fmaf(sa, xlo.w, sb * a0.w);
        o1.x = fmaf(sa, xhi.x, sb * a1.x);
        o1.y = fmaf(sa, xhi.y, sb * a1.y);
        o1.z = fmaf(sa, xhi.z, sb * a1.z);
        o1.w = fmaf(sa, xhi.w, sb * a1.w);

        float4* po = (float4*)(out + (size_t)row * D_);
        po[0] = o0;
        po[1] = o1;
    }
}

extern "C" void kernel_launch(void* const* d_in, const int* in_sizes, int n_in,
                              void* d_out, int out_size, void* d_ws, size_t ws_size,
                              hipStream_t stream) {
    const float* x       = (const float*)d_in[0];  // x_start [16,2048,4,2]
    const float* anchors = (const float*)d_in[1];  // anchors [8192,4,2]
    const float* sa_tab  = (const float*)d_in[2];  // sqrt_alphas_cumprod [1000]
    const float* sb_tab  = (const float*)d_in[3];  // sqrt_one_minus_alphas_cumprod [1000]
    const int*   t       = (const int*)d_in[4];    // t [16]
    float* out = (float*)d_out;

    // ws layout: wsv [32][ROWS] f32 = 4MB @0, packed anchors 426KB @4MB
    float* wsv = (float*)d_ws;
    char*  pk  = (char*)d_ws + (size_t)4 * 1024 * 1024;

    prep_kernel<<<M_ / 256, 256, 0, stream>>>(anchors, pk);

    dim3 gridA(GRIDX, QUARTERS);   // 128 x 8 = 1024 blocks (4/CU)
    argmin_mfma_kernel<<<gridA, 256, 0, stream>>>(x, pk, wsv);

    rescan_kernel<<<ROWS / BROWS, 256, 0, stream>>>(
        x, anchors, sa_tab, sb_tab, t, wsv, out);
}